// Round 4
// baseline (235.699 us; speedup 1.0000x reference)
//
#include <hip/hip_runtime.h>
#include <math.h>

// Problem constants (match reference setup_inputs)
#define B_  128
#define S_  512
#define D_  768
#define M_  64   // MAX_CLS

// Barrier-free, 2 m-slots per wave, branchless dual-row gather:
//   total waves = B * M/2 = 4096 ; grid = 1024 blocks x 256 threads (4 waves).
//   gw = blockIdx.x*4 + wave ; b = gw>>5 ; g = gw&31 ; slots m1 = g, m2 = g+32.
//   Each wave INDEPENDENTLY (no LDS, no __syncthreads):
//     1) one ballot-scan of cls[b,:] finds positions of the m1-th and m2-th set
//        bits (wave-uniform via ballot+ffs),
//     2) BOTH rows' 3 float4 loads issued unconditionally back-to-back
//        (invalid slot -> row 0, result masked by 0/1 flag) so 6 gather loads
//        are in flight concurrently -> single HBM-latency exposure, not two,
//     3) fused dual reduction: xor-32 fold per sum, half-select, shared 5-step
//        xor butterfly -> lane 0 holds sum1, lane 32 holds sum2,
//     4) sigmoid + store.
//   1024 blocks -> 4 blocks/CU -> 16 waves/CU.
__global__ __launch_bounds__(256, 4) void Summarizer_fused_kernel(
    const float* __restrict__ enc,
    const float* __restrict__ W,
    const float* __restrict__ bias,
    const int*   __restrict__ cls,
    float*       __restrict__ out) {

    const int tid  = threadIdx.x;
    const int lane = tid & 63;
    const int wave = tid >> 6;                    // 0..3
    const int gw   = blockIdx.x * 4 + wave;       // global wave id, 0..4095
    const int b    = gw >> 5;                     // batch, 0..127
    const int g    = gw & 31;
    const int m1   = g;                           // lower m-slot
    const int m2   = g + 32;                      // upper m-slot

    // ---- Preload W into registers (independent loads, issued first) ----
    const float4* w4 = (const float4*)W;
    const float4 w0 = w4[lane];
    const float4 w1 = w4[lane + 64];
    const float4 w2 = w4[lane + 128];
    const float  bb = bias[0];

    // ---- One ballot-scan: positions of the m1-th and m2-th set bits ----
    const int* row = cls + (size_t)b * S_;
    int base = 0;
    int pos1 = -1, pos2 = -1;
    #pragma unroll
    for (int i = 0; i < S_ / 64; ++i) {
        const int v = row[i * 64 + lane];
        const unsigned long long mask  = __ballot(v != 0);
        const unsigned long long below = mask & ((1ull << lane) - 1ull);
        const int rank = base + __popcll(below);
        const unsigned long long sel1 = __ballot((v != 0) & (rank == m1));
        const unsigned long long sel2 = __ballot((v != 0) & (rank == m2));
        if (sel1 != 0) pos1 = i * 64 + (__ffsll((unsigned long long)sel1) - 1);
        if (sel2 != 0) pos2 = i * 64 + (__ffsll((unsigned long long)sel2) - 1);
        base += __popcll(mask);
    }
    // posK >= 0  iff  mK < count(b)   (counts <= 64 == M_)

    // ---- Branchless dual-row gather: all 6 float4 loads in flight at once ----
    const float f1 = (pos1 >= 0) ? 1.0f : 0.0f;
    const float f2 = (pos2 >= 0) ? 1.0f : 0.0f;
    const int   p1 = (pos1 >= 0) ? pos1 : 0;
    const int   p2 = (pos2 >= 0) ? pos2 : 0;

    const float*  encb = enc + (size_t)b * S_ * D_;
    const float4* ra   = (const float4*)(encb + (size_t)p1 * D_);
    const float4* rb   = (const float4*)(encb + (size_t)p2 * D_);

    const float4 a0 = ra[lane];
    const float4 a1 = ra[lane + 64];
    const float4 a2 = ra[lane + 128];
    const float4 b0 = rb[lane];
    const float4 b1 = rb[lane + 64];
    const float4 b2 = rb[lane + 128];

    float s1 = a0.x * w0.x + a0.y * w0.y + a0.z * w0.z + a0.w * w0.w
             + a1.x * w1.x + a1.y * w1.y + a1.z * w1.z + a1.w * w1.w
             + a2.x * w2.x + a2.y * w2.y + a2.z * w2.z + a2.w * w2.w;
    float s2 = b0.x * w0.x + b0.y * w0.y + b0.z * w0.z + b0.w * w0.w
             + b1.x * w1.x + b1.y * w1.y + b1.z * w1.z + b1.w * w1.w
             + b2.x * w2.x + b2.y * w2.y + b2.z * w2.z + b2.w * w2.w;
    s1 *= f1;
    s2 *= f2;

    // ---- Fused dual reduction ----
    // xor-32 fold: a/c hold pairwise sums (full coverage) in every lane.
    const float pa = s1 + __shfl_xor(s1, 32, 64);
    const float pc = s2 + __shfl_xor(s2, 32, 64);
    float r = (lane < 32) ? pa : pc;
    // xor butterfly 16..1 stays closed within each 32-lane half:
    // lower half converges to sum1, upper half to sum2.
    #pragma unroll
    for (int off = 16; off > 0; off >>= 1) {
        r += __shfl_xor(r, off, 64);
    }

    if (lane == 0) {
        out[(size_t)b * M_ + m1] = 1.0f / (1.0f + __expf(-(r + bb)));
    }
    if (lane == 32) {
        out[(size_t)b * M_ + m2] = 1.0f / (1.0f + __expf(-(r + bb)));
    }
}

extern "C" void kernel_launch(void* const* d_in, const int* in_sizes, int n_in,
                              void* d_out, int out_size, void* d_ws, size_t ws_size,
                              hipStream_t stream) {
    const float* enc  = (const float*)d_in[0];   // (B,S,D) fp32
    const float* W    = (const float*)d_in[1];   // (D,1)  fp32
    const float* bias = (const float*)d_in[2];   // (1,)   fp32
    const int*   cls  = (const int*)d_in[3];     // (B,S)  bool -> int32

    float* out = (float*)d_out;                  // (B,M,1) fp32

    Summarizer_fused_kernel<<<(B_ * M_) / 8, 256, 0, stream>>>(enc, W, bias, cls, out);
}

// Round 6
// 232.114 us; speedup vs baseline: 1.0154x; 1.0154x over previous
//
#include <hip/hip_runtime.h>
#include <math.h>

// Problem constants (match reference setup_inputs)
#define B_  128
#define S_  512
#define D_  768
#define M_  64   // MAX_CLS

// ext-vector float4 so __builtin_nontemporal_load applies cleanly.
typedef float f4v __attribute__((ext_vector_type(4)));

// Barrier-free, 2 m-slots per wave, branchless dual-row gather.
//   total waves = B * M/2 = 4096 ; grid = 1024 blocks x 256 threads (4 waves).
//   gw = blockIdx.x*4 + wave ; b = gw>>5 ; g = gw&31 ; slots m1 = g, m2 = g+32.
//   Each wave INDEPENDENTLY (no LDS, no __syncthreads):
//     1) one ballot-scan of cls[b,:] finds positions of the m1-th and m2-th set
//        bits (wave-uniform via ballot+ffs),
//     2) BOTH rows' 3 float4 loads issued unconditionally back-to-back
//        (invalid slot -> row 0, result masked by 0/1 flag); enc rows are
//        use-once so loaded NONTEMPORAL (keep L2 for cls + fills),
//     3) fused dual reduction: xor-32 fold per sum, half-select, shared 5-step
//        xor butterfly -> lane 0 holds sum1, lane 32 holds sum2,
//     4) sigmoid + store.
//   NOTE (floor evidence, round 4): kernel-resident time is <10 us by traffic
//   arithmetic; measured dur_us ~236 is dominated by harness re-poison
//   fillBuffer dispatches (~2 x 122 us at 82% HBM peak). This round re-runs
//   the A/B confirming that theory (round-5 submission never got a chip).
__global__ __launch_bounds__(256, 4) void Summarizer_fused_kernel(
    const float* __restrict__ enc,
    const float* __restrict__ W,
    const float* __restrict__ bias,
    const int*   __restrict__ cls,
    float*       __restrict__ out) {

    const int tid  = threadIdx.x;
    const int lane = tid & 63;
    const int wave = tid >> 6;                    // 0..3
    const int gw   = blockIdx.x * 4 + wave;       // global wave id, 0..4095
    const int b    = gw >> 5;                     // batch, 0..127
    const int g    = gw & 31;
    const int m1   = g;                           // lower m-slot
    const int m2   = g + 32;                      // upper m-slot

    // ---- Preload W into registers (independent loads, issued first) ----
    const float4* w4 = (const float4*)W;
    const float4 w0 = w4[lane];
    const float4 w1 = w4[lane + 64];
    const float4 w2 = w4[lane + 128];
    const float  bb = bias[0];

    // ---- One ballot-scan: positions of the m1-th and m2-th set bits ----
    const int* row = cls + (size_t)b * S_;
    // Hoist all 8 cls loads so they are simultaneously in flight.
    int v[S_ / 64];
    #pragma unroll
    for (int i = 0; i < S_ / 64; ++i) v[i] = row[i * 64 + lane];

    int base = 0;
    int pos1 = -1, pos2 = -1;
    #pragma unroll
    for (int i = 0; i < S_ / 64; ++i) {
        const unsigned long long mask  = __ballot(v[i] != 0);
        const unsigned long long below = mask & ((1ull << lane) - 1ull);
        const int rank = base + __popcll(below);
        const unsigned long long sel1 = __ballot((v[i] != 0) & (rank == m1));
        const unsigned long long sel2 = __ballot((v[i] != 0) & (rank == m2));
        if (sel1 != 0) pos1 = i * 64 + (__ffsll((unsigned long long)sel1) - 1);
        if (sel2 != 0) pos2 = i * 64 + (__ffsll((unsigned long long)sel2) - 1);
        base += __popcll(mask);
    }
    // posK >= 0  iff  mK < count(b)   (counts <= 64 == M_)

    // ---- Branchless dual-row gather: all 6 float4 loads in flight at once ----
    const float f1 = (pos1 >= 0) ? 1.0f : 0.0f;
    const float f2 = (pos2 >= 0) ? 1.0f : 0.0f;
    const int   p1 = (pos1 >= 0) ? pos1 : 0;
    const int   p2 = (pos2 >= 0) ? pos2 : 0;

    const float* encb = enc + (size_t)b * S_ * D_;
    const f4v*   ra   = (const f4v*)(encb + (size_t)p1 * D_);
    const f4v*   rb   = (const f4v*)(encb + (size_t)p2 * D_);

    const f4v a0 = __builtin_nontemporal_load(ra + lane);
    const f4v a1 = __builtin_nontemporal_load(ra + lane + 64);
    const f4v a2 = __builtin_nontemporal_load(ra + lane + 128);
    const f4v b0 = __builtin_nontemporal_load(rb + lane);
    const f4v b1 = __builtin_nontemporal_load(rb + lane + 64);
    const f4v b2 = __builtin_nontemporal_load(rb + lane + 128);

    float s1 = a0.x * w0.x + a0.y * w0.y + a0.z * w0.z + a0.w * w0.w
             + a1.x * w1.x + a1.y * w1.y + a1.z * w1.z + a1.w * w1.w
             + a2.x * w2.x + a2.y * w2.y + a2.z * w2.z + a2.w * w2.w;
    float s2 = b0.x * w0.x + b0.y * w0.y + b0.z * w0.z + b0.w * w0.w
             + b1.x * w1.x + b1.y * w1.y + b1.z * w1.z + b1.w * w1.w
             + b2.x * w2.x + b2.y * w2.y + b2.z * w2.z + b2.w * w2.w;
    s1 *= f1;
    s2 *= f2;

    // ---- Fused dual reduction ----
    const float pa = s1 + __shfl_xor(s1, 32, 64);
    const float pc = s2 + __shfl_xor(s2, 32, 64);
    float r = (lane < 32) ? pa : pc;
    // xor butterfly 16..1 stays closed within each 32-lane half:
    // lower half converges to sum1, upper half to sum2.
    #pragma unroll
    for (int off = 16; off > 0; off >>= 1) {
        r += __shfl_xor(r, off, 64);
    }

    if (lane == 0) {
        out[(size_t)b * M_ + m1] = 1.0f / (1.0f + __expf(-(r + bb)));
    }
    if (lane == 32) {
        out[(size_t)b * M_ + m2] = 1.0f / (1.0f + __expf(-(r + bb)));
    }
}

extern "C" void kernel_launch(void* const* d_in, const int* in_sizes, int n_in,
                              void* d_out, int out_size, void* d_ws, size_t ws_size,
                              hipStream_t stream) {
    const float* enc  = (const float*)d_in[0];   // (B,S,D) fp32
    const float* W    = (const float*)d_in[1];   // (D,1)  fp32
    const float* bias = (const float*)d_in[2];   // (1,)   fp32
    const int*   cls  = (const int*)d_in[3];     // (B,S)  bool -> int32

    float* out = (float*)d_out;                  // (B,M,1) fp32

    Summarizer_fused_kernel<<<(B_ * M_) / 8, 256, 0, stream>>>(enc, W, bias, cls, out);
}